// Round 2
// baseline (350.344 us; speedup 1.0000x reference)
//
#include <hip/hip_runtime.h>

// MemN2N: B=64, S=4096, D=256, hops=3 (fp32).
// Algebraic reduction: softmax over a size-1 axis == 1, so attention weights
// are exactly the memory-validity mask, hop-independent. Hence
//   x = sum_{s < len_b - 1} sentences[b,s,:]      (the only real HBM traffic)
//   out = query0 + hops sequential adds of (x @ W)
// Memory-bound on the masked column-sum (~134 MB expected of the 256 MB tensor;
// invalid-region blocks early-exit without touching HBM).

#define BN 64
#define SN 4096
#define DN 256
#define CHUNKS 32
#define CHUNK_ROWS (SN / CHUNKS) // 128

// ---------------- Kernel A: per-example valid lengths ----------------
// Mask dtype is detected at runtime from word 0 (lengths >= 2 guarantees the
// first two elements are true):
//   word0 == 1          -> int32 0/1 elements
//   word0 == 0x3f800000 -> float32 0.0/1.0 elements (defensive)
//   else (>= 0x0101)    -> packed bool bytes 0x00/0x01
__global__ void k_lengths(const unsigned int* __restrict__ mask_words,
                          int* __restrict__ lengths) {
    const int b = blockIdx.x;
    const int t = threadIdx.x;
    const unsigned int w0 = mask_words[0];
    const int mode = (w0 == 1u) ? 0 : (w0 == 0x3f800000u) ? 1 : 2;
    const int words_per_row = (mode == 2) ? (SN / 4) : SN;
    const unsigned int* row = mask_words + (size_t)b * words_per_row;
    int sum = 0;
    if (mode == 2) {
        for (int i = t; i < words_per_row; i += 256)
            sum += __popc(row[i]);            // bytes are 0x00/0x01
    } else if (mode == 0) {
        for (int i = t; i < words_per_row; i += 256)
            sum += (int)row[i];               // ints are 0/1
    } else {
        for (int i = t; i < words_per_row; i += 256)
            sum += (row[i] != 0u) ? 1 : 0;    // floats are 0.0f/1.0f
    }
    #pragma unroll
    for (int off = 32; off > 0; off >>= 1)
        sum += __shfl_down(sum, off, 64);
    __shared__ int red[4];
    const int wave = t >> 6, lane = t & 63;
    if (lane == 0) red[wave] = sum;
    __syncthreads();
    if (t == 0)
        lengths[b] = red[0] + red[1] + red[2] + red[3];
}

// ---------------- Kernel B: chunked masked column-sum ----------------
// Block (c, b) sums rows s in [c*128, min((c+1)*128, len[b]-1)) of
// sentences[b] into partials[b][c][0..255]. float4 loads: 16 B/lane, 64
// lanes cover one 1 KB row, 4 row-groups per 256-thread block. Blocks
// entirely past the valid region write zeros (partials needs no pre-init).
__global__ void k_colsum(const float* __restrict__ sent,
                         const int* __restrict__ lengths,
                         float* __restrict__ partials) {
    const int c = blockIdx.x;
    const int b = blockIdx.y;
    const int t = threadIdx.x;
    const int limit = lengths[b] - 1;          // memory rows: s < limit
    const int s0 = c * CHUNK_ROWS;
    const int d4 = (t & 63) * 4;               // this thread's 4 columns
    const int g = t >> 6;                      // row group 0..3
    float4 acc = make_float4(0.f, 0.f, 0.f, 0.f);
    int nrows = limit - s0;
    if (nrows > CHUNK_ROWS) nrows = CHUNK_ROWS;
    if (nrows > 0) {
        const float* base = sent + ((size_t)b * SN + s0) * DN + d4;
        #pragma unroll 4
        for (int r = g; r < nrows; r += 4) {
            const float4 v = *reinterpret_cast<const float4*>(base + (size_t)r * DN);
            acc.x += v.x; acc.y += v.y; acc.z += v.z; acc.w += v.w;
        }
    }
    __shared__ float4 red[256];
    red[t] = acc;
    __syncthreads();
    if (t < 64) {
        const float4 a0 = red[t];
        const float4 a1 = red[64 + t];
        const float4 a2 = red[128 + t];
        const float4 a3 = red[192 + t];
        float4 o;
        o.x = a0.x + a1.x + a2.x + a3.x;
        o.y = a0.y + a1.y + a2.y + a3.y;
        o.z = a0.z + a1.z + a2.z + a3.z;
        o.w = a0.w + a1.w + a2.w + a3.w;
        float4* dst = reinterpret_cast<float4*>(
            partials + ((size_t)b * CHUNKS + c) * DN);
        dst[t] = o;
    }
}

// ---------------- Kernel C: combine + GEMV + epilogue ----------------
// One block per example. x[d] = sum of partials over chunks; stage x in LDS;
// each thread d computes (x@W)[d] (W reads coalesced across d, L2-resident
// after the first block touches it); out = q0 + hops sequential adds of x@W
// (bitwise-equivalent to the reference's repeated `query = x@W + query`).
__global__ void k_final(const float* __restrict__ sent,
                        const float* __restrict__ Wm,
                        const int* __restrict__ lengths,
                        const float* __restrict__ partials,
                        const int* __restrict__ hops_ptr,
                        float* __restrict__ out) {
    const int b = blockIdx.x;
    const int d = threadIdx.x;                 // 256 threads == D
    float x = 0.f;
    const float* p = partials + (size_t)b * CHUNKS * DN + d;
    #pragma unroll
    for (int c = 0; c < CHUNKS; ++c)
        x += p[c * DN];
    __shared__ float xs[DN];
    xs[d] = x;
    __syncthreads();
    const int len = lengths[b];
    const float q0 = sent[((size_t)b * SN + (len - 1)) * DN + d];
    float acc = 0.f;
    #pragma unroll 8
    for (int k = 0; k < DN; ++k)
        acc = fmaf(xs[k], Wm[k * DN + d], acc);
    const int hops = hops_ptr[0];              // low word also correct if int64
    float r = q0;
    for (int i = 0; i < hops; ++i)
        r += acc;
    out[b * DN + d] = r;
}

extern "C" void kernel_launch(void* const* d_in, const int* in_sizes, int n_in,
                              void* d_out, int out_size, void* d_ws, size_t ws_size,
                              hipStream_t stream) {
    const float* sent = (const float*)d_in[0];
    const unsigned int* mask = (const unsigned int*)d_in[1];
    const float* Wm = (const float*)d_in[2];
    const int* hops = (const int*)d_in[3];
    float* out = (float*)d_out;

    // workspace: [0,256) lengths (64 ints); [1024, 1024+2MB) partials
    int* lengths = (int*)d_ws;
    float* partials = (float*)((char*)d_ws + 1024);

    k_lengths<<<dim3(BN), dim3(256), 0, stream>>>(mask, lengths);
    k_colsum<<<dim3(CHUNKS, BN), dim3(256), 0, stream>>>(sent, lengths, partials);
    k_final<<<dim3(BN), dim3(256), 0, stream>>>(sent, Wm, lengths, partials, hops, out);
}